// Round 12
// baseline (848.401 us; speedup 1.0000x reference)
//
#include <hip/hip_runtime.h>

#define DIM   768
#define NH    12
#define HD    64
#define SEQ   4096
#define NB    2
#define ROWS  (NB*SEQ)        // 8192
#define QKVN  (3*DIM)         // 2304
// Q pre-scaled by 1/sqrt(64) * log2(e): softmax runs in exp2 domain.
#define QSCALE (0.125f * 1.44269504088896341f)

typedef unsigned short u16;
typedef __bf16 bf16x8 __attribute__((ext_vector_type(8)));
typedef float  f32x4  __attribute__((ext_vector_type(4)));

#if __has_builtin(__builtin_amdgcn_exp2f)
#define EXP2(x) __builtin_amdgcn_exp2f(x)
#else
#define EXP2(x) __expf((x) * 0.69314718055994531f)
#endif

__device__ __forceinline__ u16 bfc(float f) {        // native RNE f32->bf16
  __bf16 h = (__bf16)f;
  return __builtin_bit_cast(u16, h);
}

__device__ __forceinline__ unsigned cvtpk(float a, float b) {
  unsigned r;
  asm("v_cvt_pk_bf16_f32 %0, %1, %2" : "=v"(r) : "v"(a), "v"(b));
  return r;
}

__device__ __forceinline__ void gll16(const void* g, void* l) {
  __builtin_amdgcn_global_load_lds(
      (const __attribute__((address_space(1))) unsigned*)g,
      (__attribute__((address_space(3))) unsigned*)l, 16, 0, 0);
}

__device__ __forceinline__ f32x4 mfma16(bf16x8 a, bf16x8 b, f32x4 c) {
  return __builtin_amdgcn_mfma_f32_16x16x32_bf16(a, b, c, 0, 0, 0);
}

__device__ __forceinline__ f32x4 vmax4(f32x4 a, f32x4 b) {
  f32x4 r;
  r[0] = fmaxf(a[0], b[0]); r[1] = fmaxf(a[1], b[1]);
  r[2] = fmaxf(a[2], b[2]); r[3] = fmaxf(a[3], b[3]);
  return r;
}

// ---------------- prep kernels ----------------
__global__ __launch_bounds__(256) void k_cvt_x(const float* __restrict__ x,
                                               u16* __restrict__ xb) {
  int i = blockIdx.x * 256 + threadIdx.x;
  const float4* x4 = (const float4*)x;
  float4 a = x4[2 * i], b = x4[2 * i + 1];
  uint4 o;
  o.x = cvtpk(a.x, a.y); o.y = cvtpk(a.z, a.w);
  o.z = cvtpk(b.x, b.y); o.w = cvtpk(b.z, b.w);
  ((uint4*)xb)[i] = o;
}

__global__ __launch_bounds__(256) void k_prep_w(
    const float* __restrict__ Wq, const float* __restrict__ Wk,
    const float* __restrict__ Wv, const float* __restrict__ Wo,
    const float* __restrict__ bq, const float* __restrict__ bk,
    const float* __restrict__ bv,
    u16* __restrict__ wt, u16* __restrict__ wot, float* __restrict__ bqkv) {
  __shared__ float tile[32][33];
  const int z = blockIdx.y;
  const float* W = (z == 0) ? Wq : (z == 1) ? Wk : (z == 2) ? Wv : Wo;
  const int tj = blockIdx.x % 24, tk = blockIdx.x / 24;
  const int tx = threadIdx.x & 31, ty = threadIdx.x >> 5;
  #pragma unroll
  for (int yy = 0; yy < 32; yy += 8)
    tile[ty + yy][tx] = W[(size_t)(tk * 32 + ty + yy) * DIM + tj * 32 + tx];
  __syncthreads();
  u16* dst = (z < 3) ? (wt + (size_t)z * DIM * DIM) : wot;
  #pragma unroll
  for (int yy = 0; yy < 32; yy += 8)
    dst[(size_t)(tj * 32 + ty + yy) * DIM + tk * 32 + tx] = bfc(tile[tx][ty + yy]);
  if (z < 3 && blockIdx.x == 0) {
    const float* bb = (z == 0) ? bq : (z == 1) ? bk : bv;
    for (int i = threadIdx.x; i < DIM; i += 256) bqkv[z * DIM + i] = bb[i];
  }
}

// ---------------- BMx128 BK=64 bf16 MFMA GEMM (B^T input) ----------------
template <int EPI, int MI>
__global__ __launch_bounds__(256, 2) void k_gemm(
    const u16* __restrict__ A, const u16* __restrict__ Bt,
    const float* __restrict__ bias,
    u16* __restrict__ qb, u16* __restrict__ kb, u16* __restrict__ vtb,
    float* __restrict__ out, int tiles_n) {
  __shared__ alignas(16) u16 As[MI * 32 * 64];
  __shared__ alignas(16) u16 Bs[128 * 64];
  const int t  = threadIdx.x;
  const int tn = (blockIdx.x % tiles_n) * 128;
  const int tm = (blockIdx.x / tiles_n) * (MI * 32);
  const int l = t & 63, w = t >> 6;
  const int lr = l & 15, hi = l >> 4;
  const int wr = (w >> 1) * (MI * 16), wc = (w & 1) * 64;

  const int srow = t >> 3;
  const int sc16 = (t & 7) ^ (srow & 7);
  const u16* gA = A  + (size_t)(tm + srow) * DIM + sc16 * 8;
  const u16* gB = Bt + (size_t)(tn + srow) * DIM + sc16 * 8;
  u16* lA = &As[t * 8];
  u16* lB = &Bs[t * 8];

  const f32x4 vzero = {0.f, 0.f, 0.f, 0.f};
  f32x4 acc[MI][4];
  #pragma unroll
  for (int m = 0; m < MI; ++m)
    #pragma unroll
    for (int n = 0; n < 4; ++n) acc[m][n] = vzero;

  for (int kt = 0; kt < DIM / 64; ++kt) {
    const int k0 = kt * 64;
    #pragma unroll
    for (int s = 0; s < MI; ++s)
      gll16(gA + (size_t)s * 32 * DIM + k0, lA + s * 2048);
    #pragma unroll
    for (int s = 0; s < 4; ++s)
      gll16(gB + (size_t)s * 32 * DIM + k0, lB + s * 2048);
    __syncthreads();
    #pragma unroll
    for (int kh = 0; kh < 2; ++kh) {
      bf16x8 af[MI], bfr[4];
      #pragma unroll
      for (int m = 0; m < MI; ++m) {
        int row = wr + m * 16 + lr;
        af[m] = *reinterpret_cast<const bf16x8*>(
            &As[row * 64 + (((kh * 4 + hi) ^ (row & 7)) * 8)]);
      }
      #pragma unroll
      for (int n = 0; n < 4; ++n) {
        int row = wc + n * 16 + lr;
        bfr[n] = *reinterpret_cast<const bf16x8*>(
            &Bs[row * 64 + (((kh * 4 + hi) ^ (row & 7)) * 8)]);
      }
      #pragma unroll
      for (int m = 0; m < MI; ++m)
        #pragma unroll
        for (int n = 0; n < 4; ++n)
          acc[m][n] = mfma16(af[m], bfr[n], acc[m][n]);
    }
    __syncthreads();
  }

  #pragma unroll
  for (int n = 0; n < 4; ++n) {
    const int gcol = tn + wc + n * 16 + lr;
    const float bb = bias[gcol];
    if (EPI == 0) {
      int which, jj;
      if (gcol < DIM)          { which = 0; jj = gcol; }
      else if (gcol < 2 * DIM) { which = 1; jj = gcol - DIM; }
      else                     { which = 2; jj = gcol - 2 * DIM; }
      const int h = jj >> 6, d = jj & 63;
      #pragma unroll
      for (int m = 0; m < MI; ++m) {
        #pragma unroll
        for (int r = 0; r < 4; ++r) {
          const int grow = tm + wr + m * 16 + hi * 4 + r;
          const int b = grow >> 12, nn = grow & (SEQ - 1);
          const int bh = b * NH + h;
          const float val = acc[m][n][r] + bb;
          if (which == 0)
            qb[((size_t)bh * SEQ + nn) * HD + d] = bfc(val * QSCALE);
          else if (which == 1)
            kb[((size_t)bh * SEQ + nn) * HD + d] = bfc(val);
          else
            vtb[((size_t)bh * HD + d) * SEQ + nn] = bfc(val);
        }
      }
    } else {
      #pragma unroll
      for (int m = 0; m < MI; ++m)
        #pragma unroll
        for (int r = 0; r < 4; ++r) {
          const int grow = tm + wr + m * 16 + hi * 4 + r;
          out[(size_t)grow * DIM + gcol] = acc[m][n][r] + bb;
        }
    }
  }
}

// ---------------- flash attention v5 ----------------
// r11 body with DOUBLED grid for occupancy: each wave now owns 16 q-rows
// (qm dimension removed), grid 1536 -> 6 blocks/CU = 6 waves/SIMD (75%).
// r11 evidence: latency-bound serial chain at 35% occupancy (grid-limited);
// FETCH already fixed by T1 swizzle (104->18.5MB, dur unchanged).
__global__ __launch_bounds__(256, 2) void k_attn(
    const u16* __restrict__ Q, const u16* __restrict__ K,
    const u16* __restrict__ Vt, u16* __restrict__ O) {
  __shared__ alignas(16) u16 P[4][16 * 72];   // per-wave P[q][kv], stride 72
  __shared__ alignas(16) float Cb[4][16];     // per-wave q-indexed broadcast
  const int t = threadIdx.x;
  const int w = t >> 6, l = t & 63;
  const int lr = l & 15, hi = l >> 4;
  // T1: XCD-contiguous remap (grid 1536 = 8 XCDs x 192 blocks = 3 heads/XCD)
  const int swz = (blockIdx.x & 7) * 192 + (blockIdx.x >> 3);
  const int bh = swz >> 6;
  const int q0 = (swz & 63) * 64 + w * 16;
  u16* Pw = P[w];
  float* Cw = Cb[w];
  const size_t base = (size_t)bh * SEQ * HD;

  bf16x8 qf[2];
  #pragma unroll
  for (int kh = 0; kh < 2; ++kh)
    qf[kh] = *reinterpret_cast<const bf16x8*>(
        &Q[base + (size_t)(q0 + lr) * HD + kh * 32 + hi * 8]);

  const f32x4 vzero = {0.f, 0.f, 0.f, 0.f};
  f32x4 o[4];
  float mrun = -3e38f;
  float lsum = 0.f;
  #pragma unroll
  for (int db = 0; db < 4; ++db) o[db] = vzero;

  for (int kt = 0; kt < SEQ / 64; ++kt) {
    const int kv0 = kt * 64;
    f32x4 s[4];
    #pragma unroll
    for (int kvn = 0; kvn < 4; ++kvn) s[kvn] = vzero;

    // swapped: A=K (row=kv), B=Q (col=q) -> lane holds one q-row's scores
    #pragma unroll
    for (int kvn = 0; kvn < 4; ++kvn) {
      #pragma unroll
      for (int kh = 0; kh < 2; ++kh) {
        bf16x8 kf = *reinterpret_cast<const bf16x8*>(
            &K[base + (size_t)(kv0 + kvn * 16 + lr) * HD + kh * 32 + hi * 8]);
        s[kvn] = mfma16(kf, qf[kh], s[kvn]);
      }
    }

    f32x4 m4 = vmax4(vmax4(s[0], s[1]), vmax4(s[2], s[3]));
    float tm = fmaxf(fmaxf(m4[0], m4[1]), fmaxf(m4[2], m4[3]));
    tm = fmaxf(tm, __shfl_xor(tm, 16));
    tm = fmaxf(tm, __shfl_xor(tm, 32));
    if (!__all(tm <= mrun + 8.0f)) {          // defer-max (T13)
      float mnew = fmaxf(mrun, tm);
      float corr = EXP2(mrun - mnew);
      mrun = mnew;
      lsum *= corr;
      Cw[lr] = corr;
      f32x4 cv = *reinterpret_cast<const f32x4*>(&Cw[hi * 4]);
      #pragma unroll
      for (int db = 0; db < 4; ++db) o[db] *= cv;
    }
    float rs = 0.f;
    #pragma unroll
    for (int kvn = 0; kvn < 4; ++kvn) {
      float p0 = EXP2(s[kvn][0] - mrun);
      float p1 = EXP2(s[kvn][1] - mrun);
      float p2 = EXP2(s[kvn][2] - mrun);
      float p3 = EXP2(s[kvn][3] - mrun);
      rs += (p0 + p1) + (p2 + p3);
      uint2 pk;
      pk.x = cvtpk(p0, p1);
      pk.y = cvtpk(p2, p3);
      *reinterpret_cast<uint2*>(&Pw[lr * 72 + kvn * 16 + hi * 4]) = pk;
    }
    rs += __shfl_xor(rs, 16);
    rs += __shfl_xor(rs, 32);
    lsum += rs;

    #pragma unroll
    for (int ks = 0; ks < 2; ++ks) {
      bf16x8 pa = *reinterpret_cast<const bf16x8*>(&Pw[lr * 72 + ks * 32 + hi * 8]);
      #pragma unroll
      for (int db = 0; db < 4; ++db) {
        bf16x8 vf = *reinterpret_cast<const bf16x8*>(
            &Vt[((size_t)bh * HD + db * 16 + lr) * SEQ + kv0 + ks * 32 + hi * 8]);
        o[db] = mfma16(pa, vf, o[db]);
      }
    }
  }

  const int b = (bh >= NH) ? 1 : 0;
  const int h = bh - b * NH;
  Cw[lr] = 1.0f / lsum;
  f32x4 iv = *reinterpret_cast<const f32x4*>(&Cw[hi * 4]);
  #pragma unroll
  for (int db = 0; db < 4; ++db)
    #pragma unroll
    for (int r = 0; r < 4; ++r) {
      const int grow = b * SEQ + q0 + hi * 4 + r;
      O[(size_t)grow * DIM + h * HD + db * 16 + lr] = bfc(o[db][r] * iv[r]);
    }
}

extern "C" void kernel_launch(void* const* d_in, const int* in_sizes, int n_in,
                              void* d_out, int out_size, void* d_ws, size_t ws_size,
                              hipStream_t stream) {
  const float* x  = (const float*)d_in[0];
  const float* Wq = (const float*)d_in[1];
  const float* bq = (const float*)d_in[2];
  const float* Wk = (const float*)d_in[3];
  const float* bk = (const float*)d_in[4];
  const float* Wv = (const float*)d_in[5];
  const float* bv = (const float*)d_in[6];
  const float* Wo = (const float*)d_in[7];
  const float* bo = (const float*)d_in[8];
  float* out = (float*)d_out;

  char* p = (char*)d_ws;
  auto take = [&](size_t bytes) {
    char* r = p; p += (bytes + 255) & ~(size_t)255; return r;
  };
  u16*   xb    = (u16*)take((size_t)ROWS * DIM * 2);
  u16*   wqkvt = (u16*)take((size_t)QKVN * DIM * 2);
  u16*   wot   = (u16*)take((size_t)DIM * DIM * 2);
  float* bqkv  = (float*)take((size_t)QKVN * 4);
  u16*   qbuf  = (u16*)take((size_t)ROWS * DIM * 2);
  u16*   kbuf  = (u16*)take((size_t)ROWS * DIM * 2);
  u16*   vtbuf = (u16*)take((size_t)ROWS * DIM * 2);
  u16*   abuf  = (u16*)take((size_t)ROWS * DIM * 2);

  k_cvt_x<<<ROWS * DIM / 8 / 256, 256, 0, stream>>>(x, xb);
  k_prep_w<<<dim3(576, 4), 256, 0, stream>>>(Wq, Wk, Wv, Wo, bq, bk, bv,
                                             wqkvt, wot, bqkv);

  k_gemm<0, 4><<<(ROWS / 128) * (QKVN / 128), 256, 0, stream>>>(
      xb, wqkvt, bqkv, qbuf, kbuf, vtbuf, nullptr, QKVN / 128);
  k_attn<<<NB * NH * (SEQ / 64), 256, 0, stream>>>(qbuf, kbuf, vtbuf, abuf);
  k_gemm<1, 2><<<(ROWS / 64) * (DIM / 128), 256, 0, stream>>>(
      abuf, wot, bo, nullptr, nullptr, nullptr, out, DIM / 128);
}

// Round 13
// 322.087 us; speedup vs baseline: 2.6341x; 2.6341x over previous
//
#include <hip/hip_runtime.h>

#define DIM   768
#define NH    12
#define HD    64
#define SEQ   4096
#define NB    2
#define ROWS  (NB*SEQ)        // 8192
#define QKVN  (3*DIM)         // 2304
// Q pre-scaled by 1/sqrt(64) * log2(e): softmax runs in exp2 domain.
#define QSCALE (0.125f * 1.44269504088896341f)

typedef unsigned short u16;
typedef __bf16 bf16x8 __attribute__((ext_vector_type(8)));
typedef float  f32x4  __attribute__((ext_vector_type(4)));

#if __has_builtin(__builtin_amdgcn_exp2f)
#define EXP2(x) __builtin_amdgcn_exp2f(x)
#else
#define EXP2(x) __expf((x) * 0.69314718055994531f)
#endif

__device__ __forceinline__ u16 bfc(float f) {        // native RNE f32->bf16
  __bf16 h = (__bf16)f;
  return __builtin_bit_cast(u16, h);
}

__device__ __forceinline__ unsigned cvtpk(float a, float b) {
  unsigned r;
  asm("v_cvt_pk_bf16_f32 %0, %1, %2" : "=v"(r) : "v"(a), "v"(b));
  return r;
}

__device__ __forceinline__ void gll16(const void* g, void* l) {
  __builtin_amdgcn_global_load_lds(
      (const __attribute__((address_space(1))) unsigned*)g,
      (__attribute__((address_space(3))) unsigned*)l, 16, 0, 0);
}

__device__ __forceinline__ f32x4 mfma16(bf16x8 a, bf16x8 b, f32x4 c) {
  return __builtin_amdgcn_mfma_f32_16x16x32_bf16(a, b, c, 0, 0, 0);
}

__device__ __forceinline__ f32x4 vmax4(f32x4 a, f32x4 b) {
  f32x4 r;
  r[0] = fmaxf(a[0], b[0]); r[1] = fmaxf(a[1], b[1]);
  r[2] = fmaxf(a[2], b[2]); r[3] = fmaxf(a[3], b[3]);
  return r;
}

// ---------------- prep kernels ----------------
__global__ __launch_bounds__(256) void k_cvt_x(const float* __restrict__ x,
                                               u16* __restrict__ xb) {
  int i = blockIdx.x * 256 + threadIdx.x;
  const float4* x4 = (const float4*)x;
  float4 a = x4[2 * i], b = x4[2 * i + 1];
  uint4 o;
  o.x = cvtpk(a.x, a.y); o.y = cvtpk(a.z, a.w);
  o.z = cvtpk(b.x, b.y); o.w = cvtpk(b.z, b.w);
  ((uint4*)xb)[i] = o;
}

__global__ __launch_bounds__(256) void k_prep_w(
    const float* __restrict__ Wq, const float* __restrict__ Wk,
    const float* __restrict__ Wv, const float* __restrict__ Wo,
    const float* __restrict__ bq, const float* __restrict__ bk,
    const float* __restrict__ bv,
    u16* __restrict__ wt, u16* __restrict__ wot, float* __restrict__ bqkv) {
  __shared__ float tile[32][33];
  const int z = blockIdx.y;
  const float* W = (z == 0) ? Wq : (z == 1) ? Wk : (z == 2) ? Wv : Wo;
  const int tj = blockIdx.x % 24, tk = blockIdx.x / 24;
  const int tx = threadIdx.x & 31, ty = threadIdx.x >> 5;
  #pragma unroll
  for (int yy = 0; yy < 32; yy += 8)
    tile[ty + yy][tx] = W[(size_t)(tk * 32 + ty + yy) * DIM + tj * 32 + tx];
  __syncthreads();
  u16* dst = (z < 3) ? (wt + (size_t)z * DIM * DIM) : wot;
  #pragma unroll
  for (int yy = 0; yy < 32; yy += 8)
    dst[(size_t)(tj * 32 + ty + yy) * DIM + tk * 32 + tx] = bfc(tile[tx][ty + yy]);
  if (z < 3 && blockIdx.x == 0) {
    const float* bb = (z == 0) ? bq : (z == 1) ? bk : bv;
    for (int i = threadIdx.x; i < DIM; i += 256) bqkv[z * DIM + i] = bb[i];
  }
}

// ---------------- BMx128 BK=64 bf16 MFMA GEMM (B^T input) ----------------
template <int EPI, int MI>
__global__ __launch_bounds__(256, 2) void k_gemm(
    const u16* __restrict__ A, const u16* __restrict__ Bt,
    const float* __restrict__ bias,
    u16* __restrict__ qb, u16* __restrict__ kb, u16* __restrict__ vtb,
    float* __restrict__ out, int tiles_n) {
  __shared__ alignas(16) u16 As[MI * 32 * 64];
  __shared__ alignas(16) u16 Bs[128 * 64];
  const int t  = threadIdx.x;
  const int tn = (blockIdx.x % tiles_n) * 128;
  const int tm = (blockIdx.x / tiles_n) * (MI * 32);
  const int l = t & 63, w = t >> 6;
  const int lr = l & 15, hi = l >> 4;
  const int wr = (w >> 1) * (MI * 16), wc = (w & 1) * 64;

  const int srow = t >> 3;
  const int sc16 = (t & 7) ^ (srow & 7);
  const u16* gA = A  + (size_t)(tm + srow) * DIM + sc16 * 8;
  const u16* gB = Bt + (size_t)(tn + srow) * DIM + sc16 * 8;
  u16* lA = &As[t * 8];
  u16* lB = &Bs[t * 8];

  const f32x4 vzero = {0.f, 0.f, 0.f, 0.f};
  f32x4 acc[MI][4];
  #pragma unroll
  for (int m = 0; m < MI; ++m)
    #pragma unroll
    for (int n = 0; n < 4; ++n) acc[m][n] = vzero;

  for (int kt = 0; kt < DIM / 64; ++kt) {
    const int k0 = kt * 64;
    #pragma unroll
    for (int s = 0; s < MI; ++s)
      gll16(gA + (size_t)s * 32 * DIM + k0, lA + s * 2048);
    #pragma unroll
    for (int s = 0; s < 4; ++s)
      gll16(gB + (size_t)s * 32 * DIM + k0, lB + s * 2048);
    __syncthreads();
    #pragma unroll
    for (int kh = 0; kh < 2; ++kh) {
      bf16x8 af[MI], bfr[4];
      #pragma unroll
      for (int m = 0; m < MI; ++m) {
        int row = wr + m * 16 + lr;
        af[m] = *reinterpret_cast<const bf16x8*>(
            &As[row * 64 + (((kh * 4 + hi) ^ (row & 7)) * 8)]);
      }
      #pragma unroll
      for (int n = 0; n < 4; ++n) {
        int row = wc + n * 16 + lr;
        bfr[n] = *reinterpret_cast<const bf16x8*>(
            &Bs[row * 64 + (((kh * 4 + hi) ^ (row & 7)) * 8)]);
      }
      #pragma unroll
      for (int m = 0; m < MI; ++m)
        #pragma unroll
        for (int n = 0; n < 4; ++n)
          acc[m][n] = mfma16(af[m], bfr[n], acc[m][n]);
    }
    __syncthreads();
  }

  #pragma unroll
  for (int n = 0; n < 4; ++n) {
    const int gcol = tn + wc + n * 16 + lr;
    const float bb = bias[gcol];
    if (EPI == 0) {
      int which, jj;
      if (gcol < DIM)          { which = 0; jj = gcol; }
      else if (gcol < 2 * DIM) { which = 1; jj = gcol - DIM; }
      else                     { which = 2; jj = gcol - 2 * DIM; }
      const int h = jj >> 6, d = jj & 63;
      #pragma unroll
      for (int m = 0; m < MI; ++m) {
        #pragma unroll
        for (int r = 0; r < 4; ++r) {
          const int grow = tm + wr + m * 16 + hi * 4 + r;
          const int b = grow >> 12, nn = grow & (SEQ - 1);
          const int bh = b * NH + h;
          const float val = acc[m][n][r] + bb;
          if (which == 0)
            qb[((size_t)bh * SEQ + nn) * HD + d] = bfc(val * QSCALE);
          else if (which == 1)
            kb[((size_t)bh * SEQ + nn) * HD + d] = bfc(val);
          else
            vtb[((size_t)bh * HD + d) * SEQ + nn] = bfc(val);
        }
      }
    } else {
      #pragma unroll
      for (int m = 0; m < MI; ++m)
        #pragma unroll
        for (int r = 0; r < 4; ++r) {
          const int grow = tm + wr + m * 16 + hi * 4 + r;
          out[(size_t)grow * DIM + gcol] = acc[m][n][r] + bb;
        }
    }
  }
}

// ---------------- flash attention v6 ----------------
// r11 body (qm=2 ILP, grid 768, T1 swizzle) + BLOCK-SHARED K/V LDS staging
// via reg-staging (coalesced global_load -> ds_write_b128 -> barrier): cuts
// per-block L1/L2 requests 4x (r12 evidence: request-throughput-bound at
// ~8.6 TB/s L2 delivery in both r11/r12). NOT global_load_lds (r8/r10 races).
// Single-buffered, loads issued before barrier #1 (T14 split) to overlap.
__global__ __launch_bounds__(256, 2) void k_attn(
    const u16* __restrict__ Q, const u16* __restrict__ K,
    const u16* __restrict__ Vt, u16* __restrict__ O) {
  __shared__ alignas(16) u16 Ksm[64 * 64];    // [kv][d], XOR-swizzled chunks
  __shared__ alignas(16) u16 Vsm[64 * 64];    // [d][kv], XOR-swizzled chunks
  __shared__ alignas(16) u16 P[4][32 * 72];   // per-wave P[q][kv], stride 72
  __shared__ alignas(16) float Cb[4][32];     // per-wave q-indexed broadcast
  const int t = threadIdx.x;
  const int w = t >> 6, l = t & 63;
  const int lr = l & 15, hi = l >> 4;
  // T1: XCD-contiguous remap (grid 768 = 8 XCDs x 96 blocks = 3 heads/XCD)
  const int swz = (blockIdx.x & 7) * 96 + (blockIdx.x >> 3);
  const int bh = swz >> 5;
  const int q0 = (swz & 31) * 128 + w * 32;
  u16* Pw = P[w];
  float* Cw = Cb[w];
  const size_t base = (size_t)bh * SEQ * HD;

  // staging geometry: wave w covers tile rows [w*16, w*16+16); lane l handles
  // row sub = l>>3 (+8 for i=1), chunk c = l&7 (coalesced 16B), LDS chunk
  // swizzled by row&7 == l>>3 (same XOR family as the proven read side).
  const int sr0 = (w << 4) + (l >> 3);             // +8 for i=1
  const int sgc = (l & 7) * 8;                     // global chunk (u16)
  const int slc = (((l & 7) ^ (l >> 3)) << 3);     // swizzled LDS chunk (u16)

  bf16x8 qf[2][2];
  #pragma unroll
  for (int qm = 0; qm < 2; ++qm)
    #pragma unroll
    for (int kh = 0; kh < 2; ++kh)
      qf[qm][kh] = *reinterpret_cast<const bf16x8*>(
          &Q[base + (size_t)(q0 + qm * 16 + lr) * HD + kh * 32 + hi * 8]);

  const f32x4 vzero = {0.f, 0.f, 0.f, 0.f};
  f32x4 o[2][4];
  float mrun[2] = {-3e38f, -3e38f};
  float lsum[2] = {0.f, 0.f};
  #pragma unroll
  for (int qm = 0; qm < 2; ++qm)
    #pragma unroll
    for (int db = 0; db < 4; ++db) o[qm][db] = vzero;

  for (int kt = 0; kt < SEQ / 64; ++kt) {
    const int kv0 = kt * 64;

    // issue staging loads BEFORE the barrier (overlap previous compute tail)
    bf16x8 kr[2], vr[2];
    #pragma unroll
    for (int i = 0; i < 2; ++i) {
      const int row = sr0 + i * 8;
      kr[i] = *reinterpret_cast<const bf16x8*>(
          &K[base + (size_t)(kv0 + row) * HD + sgc]);
      vr[i] = *reinterpret_cast<const bf16x8*>(
          &Vt[((size_t)bh * HD + row) * SEQ + kv0 + sgc]);
    }
    __syncthreads();   // all waves done reading previous tile from LDS
    #pragma unroll
    for (int i = 0; i < 2; ++i) {
      const int row = sr0 + i * 8;
      *reinterpret_cast<bf16x8*>(&Ksm[row * 64 + slc]) = kr[i];
      *reinterpret_cast<bf16x8*>(&Vsm[row * 64 + slc]) = vr[i];
    }
    __syncthreads();   // staging visible to all waves

    f32x4 s[2][4];
    #pragma unroll
    for (int qm = 0; qm < 2; ++qm)
      #pragma unroll
      for (int kvn = 0; kvn < 4; ++kvn) s[qm][kvn] = vzero;

    // swapped: A=K (row=kv), B=Q (col=q) -> lane holds one q-row's scores
    #pragma unroll
    for (int kvn = 0; kvn < 4; ++kvn) {
      #pragma unroll
      for (int kh = 0; kh < 2; ++kh) {
        bf16x8 kf = *reinterpret_cast<const bf16x8*>(
            &Ksm[(kvn * 16 + lr) * 64 + (((kh * 4 + hi) ^ (lr & 7)) * 8)]);
        s[0][kvn] = mfma16(kf, qf[0][kh], s[0][kvn]);
        s[1][kvn] = mfma16(kf, qf[1][kh], s[1][kvn]);
      }
    }

    #pragma unroll
    for (int qm = 0; qm < 2; ++qm) {
      f32x4 m4 = vmax4(vmax4(s[qm][0], s[qm][1]), vmax4(s[qm][2], s[qm][3]));
      float tm = fmaxf(fmaxf(m4[0], m4[1]), fmaxf(m4[2], m4[3]));
      tm = fmaxf(tm, __shfl_xor(tm, 16));
      tm = fmaxf(tm, __shfl_xor(tm, 32));
      if (!__all(tm <= mrun[qm] + 8.0f)) {          // defer-max (T13)
        float mnew = fmaxf(mrun[qm], tm);
        float corr = EXP2(mrun[qm] - mnew);
        mrun[qm] = mnew;
        lsum[qm] *= corr;
        Cw[qm * 16 + lr] = corr;
        f32x4 cv = *reinterpret_cast<const f32x4*>(&Cw[qm * 16 + hi * 4]);
        #pragma unroll
        for (int db = 0; db < 4; ++db) o[qm][db] *= cv;
      }
      float rs = 0.f;
      #pragma unroll
      for (int kvn = 0; kvn < 4; ++kvn) {
        float p0 = EXP2(s[qm][kvn][0] - mrun[qm]);
        float p1 = EXP2(s[qm][kvn][1] - mrun[qm]);
        float p2 = EXP2(s[qm][kvn][2] - mrun[qm]);
        float p3 = EXP2(s[qm][kvn][3] - mrun[qm]);
        rs += (p0 + p1) + (p2 + p3);
        uint2 pk;
        pk.x = cvtpk(p0, p1);
        pk.y = cvtpk(p2, p3);
        *reinterpret_cast<uint2*>(
            &Pw[(qm * 16 + lr) * 72 + kvn * 16 + hi * 4]) = pk;
      }
      rs += __shfl_xor(rs, 16);
      rs += __shfl_xor(rs, 32);
      lsum[qm] += rs;
    }

    #pragma unroll
    for (int ks = 0; ks < 2; ++ks) {
      bf16x8 pa0 = *reinterpret_cast<const bf16x8*>(&Pw[lr * 72 + ks * 32 + hi * 8]);
      bf16x8 pa1 = *reinterpret_cast<const bf16x8*>(&Pw[(16 + lr) * 72 + ks * 32 + hi * 8]);
      #pragma unroll
      for (int db = 0; db < 4; ++db) {
        bf16x8 vf = *reinterpret_cast<const bf16x8*>(
            &Vsm[(db * 16 + lr) * 64 + (((ks * 4 + hi) ^ (lr & 7)) * 8)]);
        o[0][db] = mfma16(pa0, vf, o[0][db]);
        o[1][db] = mfma16(pa1, vf, o[1][db]);
      }
    }
  }

  const int b = (bh >= NH) ? 1 : 0;
  const int h = bh - b * NH;
  Cw[lr]      = 1.0f / lsum[0];
  Cw[16 + lr] = 1.0f / lsum[1];
  f32x4 iv[2];
  iv[0] = *reinterpret_cast<const f32x4*>(&Cw[hi * 4]);
  iv[1] = *reinterpret_cast<const f32x4*>(&Cw[16 + hi * 4]);
  #pragma unroll
  for (int qm = 0; qm < 2; ++qm)
    #pragma unroll
    for (int db = 0; db < 4; ++db)
      #pragma unroll
      for (int r = 0; r < 4; ++r) {
        const int grow = b * SEQ + q0 + qm * 16 + hi * 4 + r;
        O[(size_t)grow * DIM + h * HD + db * 16 + lr] =
            bfc(o[qm][db][r] * iv[qm][r]);
      }
}

extern "C" void kernel_launch(void* const* d_in, const int* in_sizes, int n_in,
                              void* d_out, int out_size, void* d_ws, size_t ws_size,
                              hipStream_t stream) {
  const float* x  = (const float*)d_in[0];
  const float* Wq = (const float*)d_in[1];
  const float* bq = (const float*)d_in[2];
  const float* Wk = (const float*)d_in[3];
  const float* bk = (const float*)d_in[4];
  const float* Wv = (const float*)d_in[5];
  const float* bv = (const float*)d_in[6];
  const float* Wo = (const float*)d_in[7];
  const float* bo = (const float*)d_in[8];
  float* out = (float*)d_out;

  char* p = (char*)d_ws;
  auto take = [&](size_t bytes) {
    char* r = p; p += (bytes + 255) & ~(size_t)255; return r;
  };
  u16*   xb    = (u16*)take((size_t)ROWS * DIM * 2);
  u16*   wqkvt = (u16*)take((size_t)QKVN * DIM * 2);
  u16*   wot   = (u16*)take((size_t)DIM * DIM * 2);
  float* bqkv  = (float*)take((size_t)QKVN * 4);
  u16*   qbuf  = (u16*)take((size_t)ROWS * DIM * 2);
  u16*   kbuf  = (u16*)take((size_t)ROWS * DIM * 2);
  u16*   vtbuf = (u16*)take((size_t)ROWS * DIM * 2);
  u16*   abuf  = (u16*)take((size_t)ROWS * DIM * 2);

  k_cvt_x<<<ROWS * DIM / 8 / 256, 256, 0, stream>>>(x, xb);
  k_prep_w<<<dim3(576, 4), 256, 0, stream>>>(Wq, Wk, Wv, Wo, bq, bk, bv,
                                             wqkvt, wot, bqkv);

  k_gemm<0, 4><<<(ROWS / 128) * (QKVN / 128), 256, 0, stream>>>(
      xb, wqkvt, bqkv, qbuf, kbuf, vtbuf, nullptr, QKVN / 128);
  k_attn<<<NB * NH * (SEQ / 128), 256, 0, stream>>>(qbuf, kbuf, vtbuf, abuf);
  k_gemm<1, 2><<<(ROWS / 64) * (DIM / 128), 256, 0, stream>>>(
      abuf, wot, bo, nullptr, nullptr, nullptr, out, DIM / 128);
}